// Round 9
// baseline (256.925 us; speedup 1.0000x reference)
//
#include <hip/hip_runtime.h>
#include <hip/hip_bf16.h>

typedef __attribute__((ext_vector_type(8))) short short8;
typedef __attribute__((ext_vector_type(4))) float f32x4;
typedef __hip_bfloat16 bf16;

#define D_MODEL 1024
#define D_INNER 2048
#define DT_RANK 64
#define D_STATE 16
#define B_SZ 2
#define L_SEQ 1024
#define NSEG 32
#define SL 32   /* L_SEQ / NSEG */

__device__ __forceinline__ float b2f(bf16 x){ return __bfloat162float(x); }
__device__ __forceinline__ bf16  f2b(float x){ return __float2bfloat16(x); }

__device__ __forceinline__ void cvt_store8(bf16* dst, const float* s){
  union { short8 v; bf16 e[8]; } u;
  #pragma unroll
  for (int i = 0; i < 8; i++) u.e[i] = f2b(s[i]);
  *(short8*)dst = u.v;
}

__device__ __forceinline__ void gl_lds16(const bf16* g, bf16* l){
  __builtin_amdgcn_global_load_lds((const __attribute__((address_space(1))) unsigned int*)g,
                                   (__attribute__((address_space(3))) unsigned int*)l, 16, 0, 0);
}

// ---------------------------------------------------------------------------
// f32 -> bf16 bulk convert, 5 segments packed in one launch. Chunk = 8 floats.
// ---------------------------------------------------------------------------
__global__ __launch_bounds__(256) void cvt5_k(const float* s0, bf16* d0, int c0,
                                              const float* s1, bf16* d1, int c1,
                                              const float* s2, bf16* d2, int c2,
                                              const float* s3, bf16* d3, int c3,
                                              const float* s4, bf16* d4, int c4)
{
  int i = blockIdx.x * 256 + threadIdx.x;
  const float* s; bf16* d; int off;
  if      (i < c0) { s = s0; d = d0; off = i; }
  else if (i < c1) { s = s1; d = d1; off = i - c0; }
  else if (i < c2) { s = s2; d = d2; off = i - c1; }
  else if (i < c3) { s = s3; d = d3; off = i - c2; }
  else if (i < c4) { s = s4; d = d4; off = i - c3; }
  else return;
  float b[8];
  *(float4*)&b[0] = *(const float4*)(s + (size_t)off * 8);
  *(float4*)&b[4] = *(const float4*)(s + (size_t)off * 8 + 4);
  cvt_store8(d + (size_t)off * 8, b);
}

// ---------------------------------------------------------------------------
// MFMA GEMM: C(MxN) = A(MxK) @ B(NxK)^T, bf16 in, fp32 accum.
// BM=128, BN=JT*32, BK=64. LDS XOR-swizzled both-sides (16B slot ^= row&7;
// source-side via pre-swizzled global address since gl_lds writes linearly).
// XCD-bijective swizzle for L2 locality (nwg % 8 == 0).
// MODE 0: f32 store. MODE 2: bf16 store.
// ---------------------------------------------------------------------------
template<int MODE, int JT>
__global__ __launch_bounds__(256) void gemm_glds(const bf16* __restrict__ A,
                                                 const bf16* __restrict__ B,
                                                 void* __restrict__ Cout,
                                                 int M, int N, int K)
{
  constexpr int BN = JT * 32;
  constexpr int AI = 4;               // A chunks/thread: 128*64/(256*8)
  constexpr int BI = BN / 32;         // B chunks/thread: BN*64/(256*8)
  __shared__ bf16 As[128 * 64];
  __shared__ bf16 Bs[BN * 64];

  const int gx = gridDim.x;
  const int nwg = gx * gridDim.y;
  const int flat = blockIdx.y * gx + blockIdx.x;
  const int swz = (flat & 7) * (nwg >> 3) + (flat >> 3);
  const int bm = (swz / gx) * 128, bn = (swz % gx) * BN;

  const int tid  = threadIdx.x;
  const int lane = tid & 63, wave = tid >> 6;
  const int wm = (wave & 1) * 64, wn = (wave >> 1) * (JT * 16);
  const int r = lane & 15, q = lane >> 4;
  const int rx = r & 7;               // read-side swizzle key

  const bf16* asrc[AI];
  #pragma unroll
  for (int i = 0; i < AI; i++) {
    int c = i * 256 + tid;
    int row = c >> 3, sl = (c & 7) ^ (row & 7);
    asrc[i] = A + (size_t)(bm + row) * K + sl * 8;
  }
  const bf16* bsrc[BI];
  #pragma unroll
  for (int i = 0; i < BI; i++) {
    int c = i * 256 + tid;
    int row = c >> 3, sl = (c & 7) ^ (row & 7);
    bsrc[i] = B + (size_t)(bn + row) * K + sl * 8;
  }

  f32x4 acc[4][JT];
  #pragma unroll
  for (int i = 0; i < 4; i++)
    #pragma unroll
    for (int j = 0; j < JT; j++) acc[i][j] = (f32x4){0.f,0.f,0.f,0.f};

  for (int k0 = 0; k0 < K; k0 += 64) {
    #pragma unroll
    for (int i = 0; i < AI; i++)
      gl_lds16(asrc[i] + k0, &As[(i * 256 + tid) * 8]);
    #pragma unroll
    for (int i = 0; i < BI; i++)
      gl_lds16(bsrc[i] + k0, &Bs[(i * 256 + tid) * 8]);
    __syncthreads();
    #pragma unroll
    for (int ks = 0; ks < 2; ks++) {
      short8 af[4], bfr[JT];
      #pragma unroll
      for (int i = 0; i < 4; i++)
        af[i]  = *(const short8*)&As[(wm + i*16 + r) * 64 + ((q + ks*4) ^ rx) * 8];
      #pragma unroll
      for (int j = 0; j < JT; j++)
        bfr[j] = *(const short8*)&Bs[(wn + j*16 + r) * 64 + ((q + ks*4) ^ rx) * 8];
      #pragma unroll
      for (int j = 0; j < JT; j++)
        #pragma unroll
        for (int i = 0; i < 4; i++)
          acc[i][j] = __builtin_amdgcn_mfma_f32_16x16x32_bf16(af[i], bfr[j], acc[i][j], 0, 0, 0);
    }
    __syncthreads();
  }

  #pragma unroll
  for (int i = 0; i < 4; i++)
    #pragma unroll
    for (int j = 0; j < JT; j++)
      #pragma unroll
      for (int t = 0; t < 4; t++) {
        int row = bm + wm + i*16 + q*4 + t;   // C/D: col=lane&15, row=quad*4+reg
        int col = bn + wn + j*16 + r;
        float v = acc[i][j][t];
        if (MODE == 0) ((float*)Cout)[(size_t)row * N + col] = v;
        else           ((bf16*)Cout)[(size_t)row * N + col] = f2b(v);
      }
}

// ---------------------------------------------------------------------------
// x_proj GEMM: dbc(2048x96) = xs(2048x2048 bf16) @ x_proj_w(96x2048 bf16)^T.
// Also emits bf16 copy of delta_r columns (0..63) for the in-scan dt MFMA.
// ---------------------------------------------------------------------------
__global__ __launch_bounds__(256) void gemm_xproj(const bf16* __restrict__ A,
                                                  const bf16* __restrict__ W,
                                                  float* __restrict__ dbc,
                                                  bf16* __restrict__ dr)
{
  const int K = D_INNER;
  const int lane = threadIdx.x & 63, wave = threadIdx.x >> 6;
  const int mt = blockIdx.y * 4 + wave;   // 0..127
  const int nt = blockIdx.x;              // 0..5
  const int r = lane & 15, q = lane >> 4;
  const bf16* pa = A + (size_t)(mt*16 + r) * K + q*8;
  const bf16* pb = W + (size_t)(nt*16 + r) * K + q*8;
  f32x4 a0 = {0.f,0.f,0.f,0.f}, a1 = a0, a2 = a0, a3 = a0;
  for (int k0 = 0; k0 < K; k0 += 128) {
    short8 x0 = *(const short8*)(pa + k0);
    short8 w0 = *(const short8*)(pb + k0);
    short8 x1 = *(const short8*)(pa + k0 + 32);
    short8 w1 = *(const short8*)(pb + k0 + 32);
    short8 x2 = *(const short8*)(pa + k0 + 64);
    short8 w2 = *(const short8*)(pb + k0 + 64);
    short8 x3 = *(const short8*)(pa + k0 + 96);
    short8 w3 = *(const short8*)(pb + k0 + 96);
    a0 = __builtin_amdgcn_mfma_f32_16x16x32_bf16(x0, w0, a0, 0, 0, 0);
    a1 = __builtin_amdgcn_mfma_f32_16x16x32_bf16(x1, w1, a1, 0, 0, 0);
    a2 = __builtin_amdgcn_mfma_f32_16x16x32_bf16(x2, w2, a2, 0, 0, 0);
    a3 = __builtin_amdgcn_mfma_f32_16x16x32_bf16(x3, w3, a3, 0, 0, 0);
  }
  f32x4 acc = (a0 + a1) + (a2 + a3);
  #pragma unroll
  for (int t = 0; t < 4; t++) {
    int row = mt*16 + q*4 + t;
    int col = nt*16 + r;
    dbc[(size_t)row * 96 + col] = acc[t];
    if (col < DT_RANK) dr[(size_t)row * DT_RANK + col] = f2b(acc[t]);
  }
}

// ---------------------------------------------------------------------------
// Depthwise causal conv (D_CONV=4) + bias + silu, 8 channels/thread (short8).
// ---------------------------------------------------------------------------
__global__ __launch_bounds__(256) void conv_silu_k(const bf16* __restrict__ xz,
                                                   const float* __restrict__ cw,
                                                   const float* __restrict__ cb,
                                                   bf16* __restrict__ xs_b)
{
  int idx = blockIdx.x * 256 + threadIdx.x;   // over B*L*D_INNER/8
  int dg = idx & (D_INNER/8 - 1);
  int bl = idx >> 8;
  int l  = bl & (L_SEQ - 1);
  int d0 = dg * 8;
  const float4* cw4 = (const float4*)cw;      // cw is [D_INNER][4]
  float4 w[8];
  #pragma unroll
  for (int i = 0; i < 8; i++) w[i] = cw4[d0 + i];
  float acc[8];
  #pragma unroll
  for (int i = 0; i < 8; i++) acc[i] = cb[d0 + i];
  #pragma unroll
  for (int j = 0; j < 4; ++j) {
    int lp = l - 3 + j;
    if (lp >= 0) {
      short8 v = *(const short8*)(xz + (size_t)(bl - 3 + j) * (2*D_INNER) + d0);
      #pragma unroll
      for (int i = 0; i < 8; i++)
        acc[i] += ((const float*)&w[i])[j] * b2f(((const bf16*)&v)[i]);
    }
  }
  float o[8];
  #pragma unroll
  for (int i = 0; i < 8; i++) o[i] = acc[i] / (1.f + __expf(-acc[i]));
  cvt_store8(xs_b + (size_t)idx * 8, o);
}

// ---------------------------------------------------------------------------
// A_log is log(1..16) tiled here, so An[n] = -(n+1): exp(dv*An[n]) = q^(n+1),
// q = exp(-dv). Runtime-verified per thread; general-exp fallback kept.
// ---------------------------------------------------------------------------
__device__ __forceinline__ bool an_is_int(const float* An){
  bool f = true;
  #pragma unroll
  for (int n = 0; n < 16; n++) f = f & (fabsf(An[n] + (float)(n+1)) < 1e-3f);
  return f;
}

// ---------------------------------------------------------------------------
// In-scan dt_proj: compute this block's 32x256 delta tile = softplus(
// dr[seg rows] @ dt_w[d0..d0+255]^T + dt_b) into LDS via the MFMA pipe.
// Bit-identical chaining to the old gemm_dt (c = a0b0 then +a1b1, fp32 acc).
// dr staged via gl_lds with pre-swizzled global source (slot ^= row&7) so
// the A-fragment ds_reads avoid the 128B-stride bank pathology.
// ~64 MFMA + 32 softplus/thread per block -- rides the idle matrix pipe
// (round-5 lesson: the VALU version of this fusion cost 72 us).
// ---------------------------------------------------------------------------
__device__ __forceinline__ void delta_tile_mfma(const bf16* __restrict__ dr,
                                                const bf16* __restrict__ dtw,
                                                const float* __restrict__ dt_b,
                                                int b, int seg, int d0,
                                                bf16 (*dr_s)[64],
                                                float (*delta_s)[257])
{
  const int tid  = threadIdx.x;
  const int lane = tid & 63, wave = tid >> 6;
  const int r = lane & 15, q = lane >> 4;
  const int rx = r & 7;
  // stage dr rows seg*SL..+32 (pre-swizzled source, linear LDS dest)
  {
    int row = tid >> 3, slot = tid & 7;
    const bf16* src = dr + (size_t)(b*L_SEQ + seg*SL + row) * DT_RANK
                         + ((slot ^ (row & 7)) * 8);
    gl_lds16(src, &dr_s[0][0] + tid * 8);
  }
  __syncthreads();
  #pragma unroll
  for (int rt = 0; rt < 2; rt++) {
    short8 a0 = *(const short8*)&dr_s[rt*16 + r][((q    ) ^ rx) * 8];
    short8 a1 = *(const short8*)&dr_s[rt*16 + r][((4 + q) ^ rx) * 8];
    #pragma unroll
    for (int ct = 0; ct < 4; ct++) {
      int dcol = d0 + wave*64 + ct*16 + r;
      const bf16* pb = dtw + (size_t)dcol * DT_RANK + q*8;
      short8 b0 = *(const short8*)pb;
      short8 b1 = *(const short8*)(pb + 32);
      f32x4 c = {0.f,0.f,0.f,0.f};
      c = __builtin_amdgcn_mfma_f32_16x16x32_bf16(a0, b0, c, 0, 0, 0);
      c = __builtin_amdgcn_mfma_f32_16x16x32_bf16(a1, b1, c, 0, 0, 0);
      float bv = dt_b[dcol];
      #pragma unroll
      for (int t = 0; t < 4; t++) {
        float xv = c[t] + bv;
        float sp = (xv > 20.f) ? xv : log1pf(__expf(xv));
        delta_s[rt*16 + q*4 + t][wave*64 + ct*16 + r] = sp;
      }
    }
  }
  __syncthreads();
}

// ---------------------------------------------------------------------------
// Scan pass 1: per-segment local scan from h=0 -> h_end and segment Sum(delta).
// delta computed in-kernel (MFMA) -- no global delta buffer.
// ---------------------------------------------------------------------------
__global__ __launch_bounds__(256) void scan_pass1(const bf16* __restrict__ dr,
                                                  const bf16* __restrict__ dtw,
                                                  const float* __restrict__ dt_b,
                                                  const bf16* __restrict__ xs,
                                                  const float* __restrict__ dbc,
                                                  const float* __restrict__ A_log,
                                                  float* __restrict__ hseg,
                                                  float* __restrict__ Stot)
{
  __shared__ float bcs[SL][32];
  __shared__ bf16 dr_s[SL][64];
  __shared__ float delta_s[SL][257];
  const int tid = threadIdx.x;
  const int d   = blockIdx.x * 256 + tid;
  const int seg = blockIdx.y, b = blockIdx.z;
  for (int i = tid; i < SL*32; i += 256) {
    int l = i >> 5, c = i & 31;
    bcs[l][c] = dbc[((size_t)b*L_SEQ + seg*SL + l)*96 + DT_RANK + c];
  }
  delta_tile_mfma(dr, dtw, dt_b, b, seg, blockIdx.x * 256, dr_s, delta_s);

  float An[16], h[16];
  #pragma unroll
  for (int n = 0; n < 16; n++) { An[n] = -__expf(A_log[d*16 + n]); h[n] = 0.f; }
  float S = 0.f;
  if (an_is_int(An)) {
    for (int li = 0; li < SL; ++li) {
      size_t bl = (size_t)b * L_SEQ + seg*SL + li;
      float dv = delta_s[li][tid];
      float xv = b2f(xs[bl*D_INNER + d]);
      S += dv;
      float dx = dv * xv;
      float q = __expf(-dv), w = 1.f;
      #pragma unroll
      for (int n = 0; n < 16; n++) {
        w *= q;
        h[n] = w * h[n] + dx * bcs[li][n];
      }
    }
  } else {
    for (int li = 0; li < SL; ++li) {
      size_t bl = (size_t)b * L_SEQ + seg*SL + li;
      float dv = delta_s[li][tid];
      float xv = b2f(xs[bl*D_INNER + d]);
      S += dv;
      float dx = dv * xv;
      #pragma unroll
      for (int n = 0; n < 16; n++)
        h[n] = __expf(dv * An[n]) * h[n] + dx * bcs[li][n];
    }
  }
  float* hp = hseg + (((size_t)seg*B_SZ + b)*D_INNER + d) * 16;
  #pragma unroll
  for (int n = 0; n < 16; n++) hp[n] = h[n];
  Stot[((size_t)seg*B_SZ + b)*D_INNER + d] = S;
}

// ---------------------------------------------------------------------------
// Scan pass 3 with in-kernel prefix combine + in-kernel delta (MFMA):
// block (d,seg,b) builds its true h0 from per-segment h_end/Stot (s < seg),
// then re-runs the local recurrence, fuses y + D*xs, silu(z) gate, writes
// bf16 outin.
// ---------------------------------------------------------------------------
__global__ __launch_bounds__(256) void scan_pass3(const bf16* __restrict__ dr,
                                                  const bf16* __restrict__ dtw,
                                                  const float* __restrict__ dt_b,
                                                  const bf16* __restrict__ xs,
                                                  const float* __restrict__ dbc,
                                                  const float* __restrict__ A_log,
                                                  const float* __restrict__ hseg,
                                                  const float* __restrict__ Stot,
                                                  const bf16* __restrict__ xz,
                                                  const float* __restrict__ Dw,
                                                  bf16* __restrict__ outin)
{
  __shared__ float bcs[SL][32];
  __shared__ bf16 dr_s[SL][64];
  __shared__ float delta_s[SL][257];
  const int tid = threadIdx.x;
  const int d   = blockIdx.x * 256 + tid;
  const int seg = blockIdx.y, b = blockIdx.z;
  for (int i = tid; i < SL*32; i += 256) {
    int l = i >> 5, c = i & 31;
    bcs[l][c] = dbc[((size_t)b*L_SEQ + seg*SL + l)*96 + DT_RANK + c];
  }
  delta_tile_mfma(dr, dtw, dt_b, b, seg, blockIdx.x * 256, dr_s, delta_s);

  float An[16], h[16];
  #pragma unroll
  for (int n = 0; n < 16; n++) { An[n] = -__expf(A_log[d*16 + n]); h[n] = 0.f; }
  const bool fast = an_is_int(An);

  // prefix combine: h becomes the true h0 entering this segment
  if (fast) {
    for (int s = 0; s < seg; ++s) {
      size_t base = ((size_t)s*B_SZ + b)*D_INNER + d;
      float St = Stot[base];
      const float4* hp4 = (const float4*)(hseg + base*16);
      float4 e0 = hp4[0], e1 = hp4[1], e2 = hp4[2], e3 = hp4[3];
      float he[16] = {e0.x,e0.y,e0.z,e0.w, e1.x,e1.y,e1.z,e1.w,
                      e2.x,e2.y,e2.z,e2.w, e3.x,e3.y,e3.z,e3.w};
      float qs = __expf(-St), w = 1.f;
      #pragma unroll
      for (int n = 0; n < 16; n++) {
        w *= qs;
        h[n] = w * h[n] + he[n];
      }
    }
  } else {
    for (int s = 0; s < seg; ++s) {
      size_t base = ((size_t)s*B_SZ + b)*D_INNER + d;
      float St = Stot[base];
      const float4* hp4 = (const float4*)(hseg + base*16);
      float4 e0 = hp4[0], e1 = hp4[1], e2 = hp4[2], e3 = hp4[3];
      float he[16] = {e0.x,e0.y,e0.z,e0.w, e1.x,e1.y,e1.z,e1.w,
                      e2.x,e2.y,e2.z,e2.w, e3.x,e3.y,e3.z,e3.w};
      #pragma unroll
      for (int n = 0; n < 16; n++)
        h[n] = __expf(An[n]*St) * h[n] + he[n];
    }
  }

  const float Dv = Dw[d];
  if (fast) {
    for (int li = 0; li < SL; ++li) {
      size_t bl = (size_t)b * L_SEQ + seg*SL + li;
      float dv = delta_s[li][tid];
      float xv = b2f(xs[bl*D_INNER + d]);
      float dx = dv * xv;
      float q = __expf(-dv), w = 1.f;
      float y = 0.f;
      #pragma unroll
      for (int n = 0; n < 16; n++) {
        w *= q;
        h[n] = w * h[n] + dx * bcs[li][n];
        y   += h[n] * bcs[li][16 + n];
      }
      y += Dv * xv;
      float z = b2f(xz[bl*(size_t)(2*D_INNER) + D_INNER + d]);
      float g = z / (1.f + __expf(-z));
      outin[bl*D_INNER + d] = f2b(y * g);
    }
  } else {
    for (int li = 0; li < SL; ++li) {
      size_t bl = (size_t)b * L_SEQ + seg*SL + li;
      float dv = delta_s[li][tid];
      float xv = b2f(xs[bl*D_INNER + d]);
      float dx = dv * xv;
      float y = 0.f;
      #pragma unroll
      for (int n = 0; n < 16; n++) {
        h[n] = __expf(dv * An[n]) * h[n] + dx * bcs[li][n];
        y   += h[n] * bcs[li][16 + n];
      }
      y += Dv * xv;
      float z = b2f(xz[bl*(size_t)(2*D_INNER) + D_INNER + d]);
      float g = z / (1.f + __expf(-z));
      outin[bl*D_INNER + d] = f2b(y * g);
    }
  }
}

// ---------------------------------------------------------------------------
extern "C" void kernel_launch(void* const* d_in, const int* in_sizes, int n_in,
                              void* d_out, int out_size, void* d_ws, size_t ws_size,
                              hipStream_t stream)
{
  const float* x      = (const float*)d_in[0];
  const float* in_w   = (const float*)d_in[1];
  const float* conv_w = (const float*)d_in[2];
  const float* conv_b = (const float*)d_in[3];
  const float* xp_w   = (const float*)d_in[4];
  const float* dt_w   = (const float*)d_in[5];
  const float* dt_b   = (const float*)d_in[6];
  const float* A_log  = (const float*)d_in[7];
  const float* Dw     = (const float*)d_in[8];
  const float* out_w  = (const float*)d_in[9];
  float* out = (float*)d_out;

  // workspace layout (~46 MB). hseg (8 MB) overlays xb+in_wb (12 MB):
  // xb/in_wb are dead after the in_proj GEMM, hseg is written after it.
  char* p = (char*)d_ws;
  bf16*  xz    = (bf16*)p;  p += (size_t)B_SZ*L_SEQ*2*D_INNER*2;   // 16 MB
  bf16*  xs_b  = (bf16*)p;  p += (size_t)B_SZ*L_SEQ*D_INNER*2;     //  8 MB
  float* dbc   = (float*)p; p += (size_t)B_SZ*L_SEQ*96*4;          // .75MB
  bf16*  dr    = (bf16*)p;  p += (size_t)B_SZ*L_SEQ*DT_RANK*2;     // .25MB
  float* Stot  = (float*)p; p += (size_t)NSEG*B_SZ*D_INNER*4;      // .5 MB
  bf16*  outin = (bf16*)p;  p += (size_t)B_SZ*L_SEQ*D_INNER*2;     //  8 MB
  bf16*  xp_wb = (bf16*)p;  p += (size_t)(DT_RANK+2*D_STATE)*D_INNER*2; // .375MB
  bf16*  dt_wb = (bf16*)p;  p += (size_t)D_INNER*DT_RANK*2;        // .25MB
  bf16*  ow_b  = (bf16*)p;  p += (size_t)D_MODEL*D_INNER*2;        //  4 MB
  char* u = p;                                                     // union region
  bf16*  xb    = (bf16*)u;                      // 4 MB  (gemm1 only)
  bf16*  in_wb = (bf16*)(u + (size_t)B_SZ*L_SEQ*D_MODEL*2); // 8 MB (gemm1 only)
  float* hseg  = (float*)u;                     // 8 MB (scan, after gemm1)
  p += (size_t)B_SZ*L_SEQ*(D_MODEL + 2*D_INNER)*2;  // 12 MB cover

  const int M = B_SZ * L_SEQ;   // 2048

  // 0) convert f32 inputs used by GEMMs to bf16 (chunk = 8 floats)
  cvt5_k<<<4256, 256, 0, stream>>>(x, xb, 262144,
                                   in_w, in_wb, 786432,
                                   xp_w, xp_wb, 811008,
                                   dt_w, dt_wb, 827392,
                                   out_w, ow_b, 1089536);
  // 1) xz = x @ in_proj_w^T  (2048 x 4096, K=1024) -> bf16, BN=64, BK=64
  gemm_glds<2,2><<<dim3(2*D_INNER/64, M/128), 256, 0, stream>>>(xb, in_wb, xz, M, 2*D_INNER, D_MODEL);
  // 2) depthwise causal conv + silu -> xs (bf16), 8 ch/thread
  conv_silu_k<<<(M*D_INNER/8)/256, 256, 0, stream>>>(xz, conv_w, conv_b, xs_b);
  // 3) dbc = xs @ x_proj_w^T       (2048 x 96, K=2048); dr = bf16 delta_r
  gemm_xproj<<<dim3(6, M/64), 256, 0, stream>>>(xs_b, xp_wb, dbc, dr);
  // 4+5) chunked selective scan; delta computed in-kernel on the MFMA pipe
  //      (gemm_dt dispatch + 16MB delta buffer + 48MB traffic eliminated).
  scan_pass1<<<dim3(D_INNER/256, NSEG, B_SZ), 256, 0, stream>>>(dr, dt_wb, dt_b, xs_b, dbc, A_log, hseg, Stot);
  scan_pass3<<<dim3(D_INNER/256, NSEG, B_SZ), 256, 0, stream>>>(dr, dt_wb, dt_b, xs_b, dbc, A_log, hseg, Stot, xz, Dw, outin);
  // 6) out = outin @ out_proj_w^T  (2048 x 1024, K=2048) -> f32 d_out, BN=64
  gemm_glds<0,2><<<dim3(D_MODEL/64, M/128), 256, 0, stream>>>(outin, ow_b, out, M, D_MODEL, D_INNER);
}

// Round 10
// 243.590 us; speedup vs baseline: 1.0547x; 1.0547x over previous
//
#include <hip/hip_runtime.h>
#include <hip/hip_bf16.h>

typedef __attribute__((ext_vector_type(8))) short short8;
typedef __attribute__((ext_vector_type(4))) float f32x4;
typedef __hip_bfloat16 bf16;

#define D_MODEL 1024
#define D_INNER 2048
#define DT_RANK 64
#define D_STATE 16
#define B_SZ 2
#define L_SEQ 1024
#define NSEG 32
#define SL 32   /* L_SEQ / NSEG */

__device__ __forceinline__ float b2f(bf16 x){ return __bfloat162float(x); }
__device__ __forceinline__ bf16  f2b(float x){ return __float2bfloat16(x); }

__device__ __forceinline__ void cvt_store8(bf16* dst, const float* s){
  union { short8 v; bf16 e[8]; } u;
  #pragma unroll
  for (int i = 0; i < 8; i++) u.e[i] = f2b(s[i]);
  *(short8*)dst = u.v;
}

__device__ __forceinline__ void gl_lds16(const bf16* g, bf16* l){
  __builtin_amdgcn_global_load_lds((const __attribute__((address_space(1))) unsigned int*)g,
                                   (__attribute__((address_space(3))) unsigned int*)l, 16, 0, 0);
}

// ---------------------------------------------------------------------------
// f32 -> bf16 bulk convert, 5 segments packed in one launch. Chunk = 8 floats.
// ---------------------------------------------------------------------------
__global__ __launch_bounds__(256) void cvt5_k(const float* s0, bf16* d0, int c0,
                                              const float* s1, bf16* d1, int c1,
                                              const float* s2, bf16* d2, int c2,
                                              const float* s3, bf16* d3, int c3,
                                              const float* s4, bf16* d4, int c4)
{
  int i = blockIdx.x * 256 + threadIdx.x;
  const float* s; bf16* d; int off;
  if      (i < c0) { s = s0; d = d0; off = i; }
  else if (i < c1) { s = s1; d = d1; off = i - c0; }
  else if (i < c2) { s = s2; d = d2; off = i - c1; }
  else if (i < c3) { s = s3; d = d3; off = i - c2; }
  else if (i < c4) { s = s4; d = d4; off = i - c3; }
  else return;
  float b[8];
  *(float4*)&b[0] = *(const float4*)(s + (size_t)off * 8);
  *(float4*)&b[4] = *(const float4*)(s + (size_t)off * 8 + 4);
  cvt_store8(d + (size_t)off * 8, b);
}

// ---------------------------------------------------------------------------
// MFMA GEMM: C(MxN) = A(MxK) @ B(NxK)^T, bf16 in, fp32 accum.
// BM=128, BN=JT*32, BK=64. LDS XOR-swizzled both-sides (16B slot ^= row&7;
// source-side via pre-swizzled global address since gl_lds writes linearly).
// XCD-bijective swizzle for L2 locality (nwg % 8 == 0).
// MODE 0: f32 store. MODE 2: bf16 store.
// ---------------------------------------------------------------------------
template<int MODE, int JT>
__global__ __launch_bounds__(256) void gemm_glds(const bf16* __restrict__ A,
                                                 const bf16* __restrict__ B,
                                                 void* __restrict__ Cout,
                                                 int M, int N, int K)
{
  constexpr int BN = JT * 32;
  constexpr int AI = 4;               // A chunks/thread: 128*64/(256*8)
  constexpr int BI = BN / 32;         // B chunks/thread: BN*64/(256*8)
  __shared__ bf16 As[128 * 64];
  __shared__ bf16 Bs[BN * 64];

  const int gx = gridDim.x;
  const int nwg = gx * gridDim.y;
  const int flat = blockIdx.y * gx + blockIdx.x;
  const int swz = (flat & 7) * (nwg >> 3) + (flat >> 3);
  const int bm = (swz / gx) * 128, bn = (swz % gx) * BN;

  const int tid  = threadIdx.x;
  const int lane = tid & 63, wave = tid >> 6;
  const int wm = (wave & 1) * 64, wn = (wave >> 1) * (JT * 16);
  const int r = lane & 15, q = lane >> 4;
  const int rx = r & 7;               // read-side swizzle key

  const bf16* asrc[AI];
  #pragma unroll
  for (int i = 0; i < AI; i++) {
    int c = i * 256 + tid;
    int row = c >> 3, sl = (c & 7) ^ (row & 7);
    asrc[i] = A + (size_t)(bm + row) * K + sl * 8;
  }
  const bf16* bsrc[BI];
  #pragma unroll
  for (int i = 0; i < BI; i++) {
    int c = i * 256 + tid;
    int row = c >> 3, sl = (c & 7) ^ (row & 7);
    bsrc[i] = B + (size_t)(bn + row) * K + sl * 8;
  }

  f32x4 acc[4][JT];
  #pragma unroll
  for (int i = 0; i < 4; i++)
    #pragma unroll
    for (int j = 0; j < JT; j++) acc[i][j] = (f32x4){0.f,0.f,0.f,0.f};

  for (int k0 = 0; k0 < K; k0 += 64) {
    #pragma unroll
    for (int i = 0; i < AI; i++)
      gl_lds16(asrc[i] + k0, &As[(i * 256 + tid) * 8]);
    #pragma unroll
    for (int i = 0; i < BI; i++)
      gl_lds16(bsrc[i] + k0, &Bs[(i * 256 + tid) * 8]);
    __syncthreads();
    #pragma unroll
    for (int ks = 0; ks < 2; ks++) {
      short8 af[4], bfr[JT];
      #pragma unroll
      for (int i = 0; i < 4; i++)
        af[i]  = *(const short8*)&As[(wm + i*16 + r) * 64 + ((q + ks*4) ^ rx) * 8];
      #pragma unroll
      for (int j = 0; j < JT; j++)
        bfr[j] = *(const short8*)&Bs[(wn + j*16 + r) * 64 + ((q + ks*4) ^ rx) * 8];
      #pragma unroll
      for (int j = 0; j < JT; j++)
        #pragma unroll
        for (int i = 0; i < 4; i++)
          acc[i][j] = __builtin_amdgcn_mfma_f32_16x16x32_bf16(af[i], bfr[j], acc[i][j], 0, 0, 0);
    }
    __syncthreads();
  }

  #pragma unroll
  for (int i = 0; i < 4; i++)
    #pragma unroll
    for (int j = 0; j < JT; j++)
      #pragma unroll
      for (int t = 0; t < 4; t++) {
        int row = bm + wm + i*16 + q*4 + t;   // C/D: col=lane&15, row=quad*4+reg
        int col = bn + wn + j*16 + r;
        float v = acc[i][j][t];
        if (MODE == 0) ((float*)Cout)[(size_t)row * N + col] = v;
        else           ((bf16*)Cout)[(size_t)row * N + col] = f2b(v);
      }
}

// ---------------------------------------------------------------------------
// dt_proj GEMM: delta(2048x2048 f32) = softplus(dr(2048x64) @ dt_w(2048x64)^T
// + dt_b). K=64 -> barrier-free: each wave computes a 16x64 strip via 8 MFMAs
// straight from global (operands L2-resident). Epilogue staged per-wave in
// LDS (wave-synchronous, no barriers) for coalesced dwordx4 stores.
// ---------------------------------------------------------------------------
__global__ __launch_bounds__(256) void gemm_dt(const bf16* __restrict__ A,
                                               const bf16* __restrict__ W,
                                               float* __restrict__ Cout,
                                               const float* __restrict__ bias,
                                               int M, int N)
{
  __shared__ __align__(16) float stg[4][16][68];   // per-wave, +16B row pad
  const int lane = threadIdx.x & 63, wave = threadIdx.x >> 6;
  const int ntg  = N >> 6;                       // N/64 col-groups
  const int task = blockIdx.x * 4 + wave;        // 16 rows x 64 cols per task
  const int mt   = task / ntg;
  const int ng   = task - mt * ntg;
  const int r = lane & 15, q = lane >> 4;

  const bf16* pa = A + (size_t)(mt*16 + r) * DT_RANK + q*8;
  short8 a0 = *(const short8*)pa;
  short8 a1 = *(const short8*)(pa + 32);

  #pragma unroll
  for (int j = 0; j < 4; j++) {
    const bf16* pb = W + (size_t)(ng*64 + j*16 + r) * DT_RANK + q*8;
    short8 b0 = *(const short8*)pb;
    short8 b1 = *(const short8*)(pb + 32);
    f32x4 c = {0.f,0.f,0.f,0.f};
    c = __builtin_amdgcn_mfma_f32_16x16x32_bf16(a0, b0, c, 0, 0, 0);
    c = __builtin_amdgcn_mfma_f32_16x16x32_bf16(a1, b1, c, 0, 0, 0);
    float bv = bias[ng*64 + j*16 + r];
    #pragma unroll
    for (int t = 0; t < 4; t++) {
      float xv = c[t] + bv;
      float sp = (xv > 20.f) ? xv : log1pf(__expf(xv));
      stg[wave][q*4 + t][j*16 + r] = sp;
    }
  }
  // wave-synchronous copy-out: lane -> row lane>>2, 64B quarter lane&3
  {
    int row = lane >> 2, q4 = lane & 3;
    const float* src = &stg[wave][row][q4 * 16];
    float4 w0 = *(const float4*)(src);
    float4 w1 = *(const float4*)(src + 4);
    float4 w2 = *(const float4*)(src + 8);
    float4 w3 = *(const float4*)(src + 12);
    float* gdst = Cout + (size_t)(mt*16 + row) * N + ng*64 + q4*16;
    *(float4*)(gdst)      = w0;
    *(float4*)(gdst + 4)  = w1;
    *(float4*)(gdst + 8)  = w2;
    *(float4*)(gdst + 12) = w3;
  }
}

// ---------------------------------------------------------------------------
// x_proj GEMM: dbc(2048x96) = xs(2048x2048 bf16) @ x_proj_w(96x2048 bf16)^T.
// Round-10 change: split K across the 4 waves of a block (each K/4 = 512)
// with an LDS reduction -- grid (6,128) = 768 blocks = 3 blocks/CU (was 192
// blocks = 0.75/CU, latency-starved serial K=2048 dot per wave).
// Also emits bf16 copy of delta_r columns (0..63) for the dt_proj GEMM.
// ---------------------------------------------------------------------------
__global__ __launch_bounds__(256) void gemm_xproj(const bf16* __restrict__ A,
                                                  const bf16* __restrict__ W,
                                                  float* __restrict__ dbc,
                                                  bf16* __restrict__ dr)
{
  __shared__ f32x4 red[4][64];
  const int K = D_INNER;
  const int lane = threadIdx.x & 63, wave = threadIdx.x >> 6;
  const int mt = blockIdx.y;              // 0..127
  const int nt = blockIdx.x;              // 0..5
  const int r = lane & 15, q = lane >> 4;
  const bf16* pa = A + (size_t)(mt*16 + r) * K + wave*512 + q*8;
  const bf16* pb = W + (size_t)(nt*16 + r) * K + wave*512 + q*8;
  f32x4 a0 = {0.f,0.f,0.f,0.f}, a1 = a0, a2 = a0, a3 = a0;
  #pragma unroll
  for (int k0 = 0; k0 < 512; k0 += 128) {
    short8 x0 = *(const short8*)(pa + k0);
    short8 w0 = *(const short8*)(pb + k0);
    short8 x1 = *(const short8*)(pa + k0 + 32);
    short8 w1 = *(const short8*)(pb + k0 + 32);
    short8 x2 = *(const short8*)(pa + k0 + 64);
    short8 w2 = *(const short8*)(pb + k0 + 64);
    short8 x3 = *(const short8*)(pa + k0 + 96);
    short8 w3 = *(const short8*)(pb + k0 + 96);
    a0 = __builtin_amdgcn_mfma_f32_16x16x32_bf16(x0, w0, a0, 0, 0, 0);
    a1 = __builtin_amdgcn_mfma_f32_16x16x32_bf16(x1, w1, a1, 0, 0, 0);
    a2 = __builtin_amdgcn_mfma_f32_16x16x32_bf16(x2, w2, a2, 0, 0, 0);
    a3 = __builtin_amdgcn_mfma_f32_16x16x32_bf16(x3, w3, a3, 0, 0, 0);
  }
  red[wave][lane] = (a0 + a1) + (a2 + a3);
  __syncthreads();
  if (wave == 0) {
    f32x4 s0 = red[0][lane], s1 = red[1][lane];
    f32x4 s2 = red[2][lane], s3 = red[3][lane];
    f32x4 acc = (s0 + s1) + (s2 + s3);
    #pragma unroll
    for (int t = 0; t < 4; t++) {
      int row = mt*16 + q*4 + t;
      int col = nt*16 + r;
      dbc[(size_t)row * 96 + col] = acc[t];
      if (col < DT_RANK) dr[(size_t)row * DT_RANK + col] = f2b(acc[t]);
    }
  }
}

// ---------------------------------------------------------------------------
// Depthwise causal conv (D_CONV=4) + bias + silu, 8 channels/thread (short8).
// ---------------------------------------------------------------------------
__global__ __launch_bounds__(256) void conv_silu_k(const bf16* __restrict__ xz,
                                                   const float* __restrict__ cw,
                                                   const float* __restrict__ cb,
                                                   bf16* __restrict__ xs_b)
{
  int idx = blockIdx.x * 256 + threadIdx.x;   // over B*L*D_INNER/8
  int dg = idx & (D_INNER/8 - 1);
  int bl = idx >> 8;
  int l  = bl & (L_SEQ - 1);
  int d0 = dg * 8;
  const float4* cw4 = (const float4*)cw;      // cw is [D_INNER][4]
  float4 w[8];
  #pragma unroll
  for (int i = 0; i < 8; i++) w[i] = cw4[d0 + i];
  float acc[8];
  #pragma unroll
  for (int i = 0; i < 8; i++) acc[i] = cb[d0 + i];
  #pragma unroll
  for (int j = 0; j < 4; ++j) {
    int lp = l - 3 + j;
    if (lp >= 0) {
      short8 v = *(const short8*)(xz + (size_t)(bl - 3 + j) * (2*D_INNER) + d0);
      #pragma unroll
      for (int i = 0; i < 8; i++)
        acc[i] += ((const float*)&w[i])[j] * b2f(((const bf16*)&v)[i]);
    }
  }
  float o[8];
  #pragma unroll
  for (int i = 0; i < 8; i++) o[i] = acc[i] / (1.f + __expf(-acc[i]));
  cvt_store8(xs_b + (size_t)idx * 8, o);
}

// ---------------------------------------------------------------------------
// A_log is log(1..16) tiled here, so An[n] = -(n+1): exp(dv*An[n]) = q^(n+1),
// q = exp(-dv). Runtime-verified per thread; general-exp fallback kept.
// ---------------------------------------------------------------------------
__device__ __forceinline__ bool an_is_int(const float* An){
  bool f = true;
  #pragma unroll
  for (int n = 0; n < 16; n++) f = f & (fabsf(An[n] + (float)(n+1)) < 1e-3f);
  return f;
}

// ---------------------------------------------------------------------------
// Scan pass 1: per-segment local scan from h=0 -> h_end and segment Sum(delta).
// ---------------------------------------------------------------------------
__global__ __launch_bounds__(256) void scan_pass1(const float* __restrict__ delta,
                                                  const bf16* __restrict__ xs,
                                                  const float* __restrict__ dbc,
                                                  const float* __restrict__ A_log,
                                                  float* __restrict__ hseg,
                                                  float* __restrict__ Stot)
{
  __shared__ float bcs[SL][32];
  const int d   = blockIdx.x * 256 + threadIdx.x;
  const int seg = blockIdx.y, b = blockIdx.z;
  for (int i = threadIdx.x; i < SL*32; i += 256) {
    int l = i >> 5, c = i & 31;
    bcs[l][c] = dbc[((size_t)b*L_SEQ + seg*SL + l)*96 + DT_RANK + c];
  }
  __syncthreads();
  float An[16], h[16];
  #pragma unroll
  for (int n = 0; n < 16; n++) { An[n] = -__expf(A_log[d*16 + n]); h[n] = 0.f; }
  float S = 0.f;
  if (an_is_int(An)) {
    for (int li = 0; li < SL; ++li) {
      size_t bl = (size_t)b * L_SEQ + seg*SL + li;
      float dv = delta[bl*D_INNER + d];
      float xv = b2f(xs[bl*D_INNER + d]);
      S += dv;
      float dx = dv * xv;
      float q = __expf(-dv), w = 1.f;
      #pragma unroll
      for (int n = 0; n < 16; n++) {
        w *= q;
        h[n] = w * h[n] + dx * bcs[li][n];
      }
    }
  } else {
    for (int li = 0; li < SL; ++li) {
      size_t bl = (size_t)b * L_SEQ + seg*SL + li;
      float dv = delta[bl*D_INNER + d];
      float xv = b2f(xs[bl*D_INNER + d]);
      S += dv;
      float dx = dv * xv;
      #pragma unroll
      for (int n = 0; n < 16; n++)
        h[n] = __expf(dv * An[n]) * h[n] + dx * bcs[li][n];
    }
  }
  float* hp = hseg + (((size_t)seg*B_SZ + b)*D_INNER + d) * 16;
  #pragma unroll
  for (int n = 0; n < 16; n++) hp[n] = h[n];
  Stot[((size_t)seg*B_SZ + b)*D_INNER + d] = S;
}

// ---------------------------------------------------------------------------
// Scan pass 3 with in-kernel prefix combine: block (d,seg,b) first builds its
// true h0 from the (L2/L3-resident) per-segment h_end/Stot of segments < seg
// using the q^(n+1) identity (1 exp + 15 mul per segment), then re-runs the
// local recurrence, fuses y + D*xs, silu(z) gate, writes bf16 outin.
// ---------------------------------------------------------------------------
__global__ __launch_bounds__(256) void scan_pass3(const float* __restrict__ delta,
                                                  const bf16* __restrict__ xs,
                                                  const float* __restrict__ dbc,
                                                  const float* __restrict__ A_log,
                                                  const float* __restrict__ hseg,
                                                  const float* __restrict__ Stot,
                                                  const bf16* __restrict__ xz,
                                                  const float* __restrict__ Dw,
                                                  bf16* __restrict__ outin)
{
  __shared__ float bcs[SL][32];
  const int d   = blockIdx.x * 256 + threadIdx.x;
  const int seg = blockIdx.y, b = blockIdx.z;
  for (int i = threadIdx.x; i < SL*32; i += 256) {
    int l = i >> 5, c = i & 31;
    bcs[l][c] = dbc[((size_t)b*L_SEQ + seg*SL + l)*96 + DT_RANK + c];
  }
  __syncthreads();
  float An[16], h[16];
  #pragma unroll
  for (int n = 0; n < 16; n++) { An[n] = -__expf(A_log[d*16 + n]); h[n] = 0.f; }
  const bool fast = an_is_int(An);

  // prefix combine: h becomes the true h0 entering this segment
  if (fast) {
    for (int s = 0; s < seg; ++s) {
      size_t base = ((size_t)s*B_SZ + b)*D_INNER + d;
      float St = Stot[base];
      const float4* hp4 = (const float4*)(hseg + base*16);
      float4 e0 = hp4[0], e1 = hp4[1], e2 = hp4[2], e3 = hp4[3];
      float he[16] = {e0.x,e0.y,e0.z,e0.w, e1.x,e1.y,e1.z,e1.w,
                      e2.x,e2.y,e2.z,e2.w, e3.x,e3.y,e3.z,e3.w};
      float qs = __expf(-St), w = 1.f;
      #pragma unroll
      for (int n = 0; n < 16; n++) {
        w *= qs;
        h[n] = w * h[n] + he[n];
      }
    }
  } else {
    for (int s = 0; s < seg; ++s) {
      size_t base = ((size_t)s*B_SZ + b)*D_INNER + d;
      float St = Stot[base];
      const float4* hp4 = (const float4*)(hseg + base*16);
      float4 e0 = hp4[0], e1 = hp4[1], e2 = hp4[2], e3 = hp4[3];
      float he[16] = {e0.x,e0.y,e0.z,e0.w, e1.x,e1.y,e1.z,e1.w,
                      e2.x,e2.y,e2.z,e2.w, e3.x,e3.y,e3.z,e3.w};
      #pragma unroll
      for (int n = 0; n < 16; n++)
        h[n] = __expf(An[n]*St) * h[n] + he[n];
    }
  }

  const float Dv = Dw[d];
  if (fast) {
    for (int li = 0; li < SL; ++li) {
      size_t bl = (size_t)b * L_SEQ + seg*SL + li;
      float dv = delta[bl*D_INNER + d];
      float xv = b2f(xs[bl*D_INNER + d]);
      float dx = dv * xv;
      float q = __expf(-dv), w = 1.f;
      float y = 0.f;
      #pragma unroll
      for (int n = 0; n < 16; n++) {
        w *= q;
        h[n] = w * h[n] + dx * bcs[li][n];
        y   += h[n] * bcs[li][16 + n];
      }
      y += Dv * xv;
      float z = b2f(xz[bl*(size_t)(2*D_INNER) + D_INNER + d]);
      float g = z / (1.f + __expf(-z));
      outin[bl*D_INNER + d] = f2b(y * g);
    }
  } else {
    for (int li = 0; li < SL; ++li) {
      size_t bl = (size_t)b * L_SEQ + seg*SL + li;
      float dv = delta[bl*D_INNER + d];
      float xv = b2f(xs[bl*D_INNER + d]);
      float dx = dv * xv;
      float y = 0.f;
      #pragma unroll
      for (int n = 0; n < 16; n++) {
        h[n] = __expf(dv * An[n]) * h[n] + dx * bcs[li][n];
        y   += h[n] * bcs[li][16 + n];
      }
      y += Dv * xv;
      float z = b2f(xz[bl*(size_t)(2*D_INNER) + D_INNER + d]);
      float g = z / (1.f + __expf(-z));
      outin[bl*D_INNER + d] = f2b(y * g);
    }
  }
}

// ---------------------------------------------------------------------------
extern "C" void kernel_launch(void* const* d_in, const int* in_sizes, int n_in,
                              void* d_out, int out_size, void* d_ws, size_t ws_size,
                              hipStream_t stream)
{
  const float* x      = (const float*)d_in[0];
  const float* in_w   = (const float*)d_in[1];
  const float* conv_w = (const float*)d_in[2];
  const float* conv_b = (const float*)d_in[3];
  const float* xp_w   = (const float*)d_in[4];
  const float* dt_w   = (const float*)d_in[5];
  const float* dt_b   = (const float*)d_in[6];
  const float* A_log  = (const float*)d_in[7];
  const float* Dw     = (const float*)d_in[8];
  const float* out_w  = (const float*)d_in[9];
  float* out = (float*)d_out;

  // workspace layout (~62 MB). hseg (8 MB) overlays xb+in_wb (12 MB):
  // xb/in_wb are dead after the in_proj GEMM, hseg is written after it.
  char* p = (char*)d_ws;
  bf16*  xz    = (bf16*)p;  p += (size_t)B_SZ*L_SEQ*2*D_INNER*2;   // 16 MB
  bf16*  xs_b  = (bf16*)p;  p += (size_t)B_SZ*L_SEQ*D_INNER*2;     //  8 MB
  float* dbc   = (float*)p; p += (size_t)B_SZ*L_SEQ*96*4;          // .75MB
  bf16*  dr    = (bf16*)p;  p += (size_t)B_SZ*L_SEQ*DT_RANK*2;     // .25MB
  float* delta = (float*)p; p += (size_t)B_SZ*L_SEQ*D_INNER*4;     // 16 MB
  float* Stot  = (float*)p; p += (size_t)NSEG*B_SZ*D_INNER*4;      // .5 MB
  bf16*  outin = (bf16*)p;  p += (size_t)B_SZ*L_SEQ*D_INNER*2;     //  8 MB
  bf16*  xp_wb = (bf16*)p;  p += (size_t)(DT_RANK+2*D_STATE)*D_INNER*2; // .375MB
  bf16*  dt_wb = (bf16*)p;  p += (size_t)D_INNER*DT_RANK*2;        // .25MB
  bf16*  ow_b  = (bf16*)p;  p += (size_t)D_MODEL*D_INNER*2;        //  4 MB
  char* u = p;                                                     // union region
  bf16*  xb    = (bf16*)u;                      // 4 MB  (gemm1 only)
  bf16*  in_wb = (bf16*)(u + (size_t)B_SZ*L_SEQ*D_MODEL*2); // 8 MB (gemm1 only)
  float* hseg  = (float*)u;                     // 8 MB (scan, after gemm1)
  p += (size_t)B_SZ*L_SEQ*(D_MODEL + 2*D_INNER)*2;  // 12 MB cover

  const int M = B_SZ * L_SEQ;   // 2048

  // 0) convert f32 inputs used by GEMMs to bf16 (chunk = 8 floats)
  cvt5_k<<<4256, 256, 0, stream>>>(x, xb, 262144,
                                   in_w, in_wb, 786432,
                                   xp_w, xp_wb, 811008,
                                   dt_w, dt_wb, 827392,
                                   out_w, ow_b, 1089536);
  // 1) xz = x @ in_proj_w^T  (2048 x 4096, K=1024) -> bf16, BN=64, BK=64
  gemm_glds<2,2><<<dim3(2*D_INNER/64, M/128), 256, 0, stream>>>(xb, in_wb, xz, M, 2*D_INNER, D_MODEL);
  // 2) depthwise causal conv + silu -> xs (bf16), 8 ch/thread
  conv_silu_k<<<(M*D_INNER/8)/256, 256, 0, stream>>>(xz, conv_w, conv_b, xs_b);
  // 3) dbc = xs @ x_proj_w^T  (2048 x 96, K=2048); wave-split-K, 3 blocks/CU
  gemm_xproj<<<dim3(6, M/16), 256, 0, stream>>>(xs_b, xp_wb, dbc, dr);
  // 4) delta = softplus(dr @ dt_proj_w^T + dt_b)  (2048 x 2048, K=64) -> f32
  gemm_dt<<<(M/16)*(D_INNER/64)/4, 256, 0, stream>>>(dr, dt_wb, delta, dt_b, M, D_INNER);
  // 5) chunked selective scan: pass1, then pass3 with in-kernel prefix
  //    combine.
  scan_pass1<<<dim3(D_INNER/256, NSEG, B_SZ), 256, 0, stream>>>(delta, xs_b, dbc, A_log, hseg, Stot);
  scan_pass3<<<dim3(D_INNER/256, NSEG, B_SZ), 256, 0, stream>>>(delta, xs_b, dbc, A_log, hseg, Stot, xz, Dw, outin);
  // 6) out = outin @ out_proj_w^T  (2048 x 1024, K=2048) -> f32 d_out, BN=64
  gemm_glds<0,2><<<dim3(D_MODEL/64, M/128), 256, 0, stream>>>(outin, ow_b, out, M, D_MODEL, D_INNER);
}